// Round 3
// baseline (245.792 us; speedup 1.0000x reference)
//
#include <hip/hip_runtime.h>
#include <stdint.h>

#define FILTER_TH 1.5f
#define CAP 1024          // per-wave candidate cap; E[cand]=668, sigma=25 -> 14-sigma margin
#define NB 128            // histogram bins, width 1/32 over [1.5, 5.5)
#define BIN_SCALE 32.0f
#define BCAP 64           // threshold-bin cap; expected ~8 members
#define DELTA_W 0.2f
#define NITER 6           // float4 loads batched per lane

// Monotone map float -> uint32 (order-preserving), exact fallbacks only
__device__ __forceinline__ unsigned f2u(float x) {
    unsigned b = __float_as_uint(x);
    return (b & 0x80000000u) ? ~b : (b | 0x80000000u);
}
__device__ __forceinline__ float u2f(unsigned u) {
    unsigned b = (u & 0x80000000u) ? (u & 0x7fffffffu) : ~u;
    return __uint_as_float(b);
}

// In-wave LDS fence: drains this wave's DS queue so all lanes' LDS writes /
// atomics become visible wave-wide. Each wave touches ONLY its own LDS slice,
// so no s_barrier is needed anywhere in this kernel.
__device__ __forceinline__ void wave_lds_fence() {
    asm volatile("s_waitcnt lgkmcnt(0)" ::: "memory");
}

__global__ __launch_bounds__(256, 7) void dtl_rows(const float* __restrict__ in,
                                                   const int* __restrict__ targets,
                                                   float* __restrict__ ws,
                                                   int M, int N, int K) {
    __shared__ float cand[4][CAP];
    __shared__ int   hist[4][NB];
    __shared__ float bstar[4][BCAP];
    __shared__ int   scal[4][4];   // 0:cnt 1:bcnt 2:bsel 3:chi

    const int wid = threadIdx.x >> 6;
    const int lane = threadIdx.x & 63;
    const int row = blockIdx.x * 4 + wid;
    if (row >= M) return;          // wave-uniform; no barriers in this kernel

    float* __restrict__ mycand = cand[wid];
    int* __restrict__ myhist = hist[wid];
    float* __restrict__ mybst = bstar[wid];
    int* __restrict__ mys = scal[wid];

    const size_t rowoff = (size_t)row * (size_t)N;
    const float* __restrict__ p = in + rowoff;
    const int tgt = targets[row];

    float posv = 0.f;
    if (lane == 0) posv = p[tgt];  // issued early, overlaps the whole kernel

    for (int i = lane; i < NB; i += 64) myhist[i] = 0;
    if (lane < 4) mys[lane] = 0;
    wave_lds_fence();

    auto push = [&](float x) {
        int b = atomicAdd(&mys[0], 1);
        if (b < CAP) mycand[b] = x;
        int bin = (int)((x - FILTER_TH) * BIN_SCALE);
        if (bin > NB - 1) bin = NB - 1;
        atomicAdd(&myhist[bin], 1);
    };

    // ---- Pass 1: filter x > FILTER_TH (excluding target col) into LDS ----
    int a0 = (int)((4 - (rowoff & 3)) & 3);   // odd row stride -> fix alignment
    if (a0 > N) a0 = N;
    const int nv = (N - a0) >> 2;
    const int tail0 = a0 + nv * 4;

    if (lane < a0) {
        float x = p[lane];
        if (x > FILTER_TH && lane != tgt) push(x);
    }
    {
        int c = tail0 + lane;
        if (c < N) {
            float x = p[c];
            if (x > FILTER_TH && c != tgt) push(x);
        }
    }

    const float4* __restrict__ pv = (const float4*)(p + a0);
    for (int base = 0; base < nv; base += NITER * 64) {
        float4 buf[NITER];
#pragma unroll
        for (int it = 0; it < NITER; ++it) {   // all loads in flight before use
            int i = base + it * 64 + lane;
            buf[it] = (i < nv) ? pv[i]
                               : make_float4(-1e30f, -1e30f, -1e30f, -1e30f);
        }
#pragma unroll
        for (int it = 0; it < NITER; ++it) {
            int i = base + it * 64 + lane;
            int c0 = a0 + i * 4;
            float xs[4] = {buf[it].x, buf[it].y, buf[it].z, buf[it].w};
#pragma unroll
            for (int j = 0; j < 4; ++j) {
                float x = xs[j];
                if (x > FILTER_TH && (c0 + j) != tgt) push(x);
            }
        }
    }
    wave_lds_fence();
    const int nC = mys[0];
    const bool fast = (nC >= K && nC <= CAP);
    bool done = false;

    if (fast) {
        // ---- threshold bin b* + count-above chi (whole wave, in-register) --
        int h0 = myhist[lane * 2], h1 = myhist[lane * 2 + 1];
        int cum = h0 + h1;
#pragma unroll
        for (int off = 1; off < 64; off <<= 1) {   // reverse inclusive scan
            int v = __shfl_down(cum, off);
            if (lane + off < 64) cum += v;
        }
        int cn = __shfl_down(cum, 1);
        if (lane == 63) cn = 0;
        if (cum >= K && cn < K) {                  // unique crossing lane
            int cacc = cn + h1;
            if (cacc >= K) { mys[2] = lane * 2 + 1; mys[3] = cn; }
            else           { mys[2] = lane * 2;     mys[3] = cacc; }
        }
        wave_lds_fence();
        const int bsel = mys[2];
        const int chi = mys[3];

        // ---- classify: sum bins > b*, collect members of bin b* ----
        float lsum = 0.f;
        for (int i = lane; i < nC; i += 64) {
            float x = mycand[i];
            int bin = (int)((x - FILTER_TH) * BIN_SCALE);
            if (bin > NB - 1) bin = NB - 1;
            if (bin > bsel) {
                float e = 1.f + x;
                lsum += e * e;
            } else if (bin == bsel) {
                int b = atomicAdd(&mys[1], 1);
                if (b < BCAP) mybst[b] = x;
            }
        }
#pragma unroll
        for (int off = 32; off > 0; off >>= 1) lsum += __shfl_down(lsum, off);
        wave_lds_fence();
        const int mB = mys[1];
        if (mB <= BCAP) {
            if (lane == 0) {
                float sum = lsum;
                int need = K - chi;                // in [1, mB]
                for (int r = 0; r < need; ++r) {   // top-`need` of tiny bin
                    int bi = 0; float bx = -1e30f;
                    for (int i2 = 0; i2 < mB; ++i2) {
                        float x = mybst[i2];
                        if (x > bx) { bx = x; bi = i2; }
                    }
                    float e = 1.f + bx;
                    sum += e * e;
                    mybst[bi] = -1e30f;
                }
                float d = 1.f - posv;
                ws[row] = d * d + DELTA_W * sum / (float)K;
            }
            done = true;
        }
    }

    if (!done) {
        // ---- exact fallbacks (never hit for N(0,1) data) ----
        unsigned thr = 0;
        if (fast) {
            // bit-search over complete LDS candidate list
            for (int bit = 31; bit >= 0; --bit) {
                unsigned trial = thr | (1u << bit);
                int cnt = 0;
                for (int i = lane; i < nC; i += 64) cnt += (f2u(mycand[i]) >= trial);
                for (int off = 32; off > 0; off >>= 1) cnt += __shfl_down(cnt, off);
                cnt = __shfl(cnt, 0);
                if (cnt >= K) thr = trial;
            }
            int gt = 0; float s = 0.f;
            for (int i = lane; i < nC; i += 64) {
                unsigned u = f2u(mycand[i]);
                if (u > thr) { gt++; float e = 1.f + u2f(u); s += e * e; }
            }
            for (int off = 32; off > 0; off >>= 1) {
                gt += __shfl_down(gt, off); s += __shfl_down(s, off);
            }
            if (lane == 0) {
                float et = 1.f + u2f(thr);
                float sum = s + (float)(K - gt) * et * et;
                float d = 1.f - posv;
                ws[row] = d * d + DELTA_W * sum / (float)K;
            }
        } else {
            // bit-search over full global row
            for (int bit = 31; bit >= 0; --bit) {
                unsigned trial = thr | (1u << bit);
                int cnt = 0;
                for (int i = lane; i < N; i += 64) {
                    if (i == tgt) continue;
                    cnt += (f2u(p[i]) >= trial);
                }
                for (int off = 32; off > 0; off >>= 1) cnt += __shfl_down(cnt, off);
                cnt = __shfl(cnt, 0);
                if (cnt >= K) thr = trial;
            }
            int gt = 0; float s = 0.f;
            for (int i = lane; i < N; i += 64) {
                if (i == tgt) continue;
                unsigned u = f2u(p[i]);
                if (u > thr) { gt++; float e = 1.f + u2f(u); s += e * e; }
            }
            for (int off = 32; off > 0; off >>= 1) {
                gt += __shfl_down(gt, off); s += __shfl_down(s, off);
            }
            if (lane == 0) {
                float et = 1.f + u2f(thr);
                float sum = s + (float)(K - gt) * et * et;
                float d = 1.f - posv;
                ws[row] = d * d + DELTA_W * sum / (float)K;
            }
        }
    }
}

__global__ __launch_bounds__(256) void dtl_reduce(const float* __restrict__ ws,
                                                  float* __restrict__ out, int M) {
    __shared__ float sh[4];
    float s = 0.f;
    for (int i = threadIdx.x; i < M; i += 256) s += ws[i];
    for (int off = 32; off > 0; off >>= 1) s += __shfl_down(s, off);
    int wid = threadIdx.x >> 6;
    if ((threadIdx.x & 63) == 0) sh[wid] = s;
    __syncthreads();
    if (threadIdx.x == 0) out[0] = (sh[0] + sh[1] + sh[2] + sh[3]) / (float)M;
}

extern "C" void kernel_launch(void* const* d_in, const int* in_sizes, int n_in,
                              void* d_out, int out_size, void* d_ws, size_t ws_size,
                              hipStream_t stream) {
    const float* in = (const float*)d_in[0];
    const int* tgt = (const int*)d_in[1];
    const int M = in_sizes[1];
    const int N = in_sizes[0] / M;
    int K = (int)(0.01 * (double)(N - 1));  // matches Python int(R*(n-1)) = 100
    if (K < 1) K = 1;

    float* ws = (float*)d_ws;
    float* out = (float*)d_out;

    dtl_rows<<<(M + 3) / 4, 256, 0, stream>>>(in, tgt, ws, M, N, K);
    dtl_reduce<<<1, 256, 0, stream>>>(ws, out, M);
}